// Round 1
// baseline (422.276 us; speedup 1.0000x reference)
//
#include <hip/hip_runtime.h>

#define NCLS 19
#define NCH 256
#define NPIX 65536   // 256*256
#define NBATCH 4
#define TPB 256
#define EPSV 1e-5f
#define CNT_THRESH 6

// ---------------- kernel 1: per-batch label histogram -> counts + valid ----
__global__ __launch_bounds__(TPB) void count_kernel(const int* __restrict__ y,
                                                    int* __restrict__ counts,
                                                    float* __restrict__ valid_out) {
    __shared__ int h[NCLS][TPB];
    const int tid = threadIdx.x;
    const int b = blockIdx.x;
    for (int k = 0; k < NCLS; ++k) h[k][tid] = 0;
    __syncthreads();
    const int4* yp = (const int4*)(y + (size_t)b * NPIX);
    #pragma unroll 4
    for (int it = 0; it < NPIX / (TPB * 4); ++it) {
        int4 l = yp[it * TPB + tid];
        if ((unsigned)l.x < NCLS) h[l.x][tid]++;
        if ((unsigned)l.y < NCLS) h[l.y][tid]++;
        if ((unsigned)l.z < NCLS) h[l.z][tid]++;
        if ((unsigned)l.w < NCLS) h[l.w][tid]++;
    }
    for (int s = TPB / 2; s > 0; s >>= 1) {
        __syncthreads();
        if (tid < s)
            for (int k = 0; k < NCLS; ++k) h[k][tid] += h[k][tid + s];
    }
    __syncthreads();
    if (tid < NCLS) {
        int n = h[tid][0];
        counts[b * NCLS + tid] = n;
        valid_out[b * NCLS + tid] = (n > CNT_THRESH) ? 1.0f : 0.0f;
    }
}

// ---------------- kernel 2: per-(b,c) masked sum / sumsq ------------------
__global__ __launch_bounds__(TPB) void moment_kernel(const float* __restrict__ x,
                                                     const int* __restrict__ y,
                                                     const int* __restrict__ counts,
                                                     float* __restrict__ out) {
    // Thread-private per-class accumulators: acc[k][tid] = (sum, sumsq).
    // 19*256*8 = 38 KB -> 4 blocks/CU (152 KB of 160 KB LDS). Lane-stride-1
    // columns => only the free 2-way bank aliasing on b64 access.
    __shared__ float2 acc[NCLS][TPB];
    const int tid = threadIdx.x;
    const int c = blockIdx.x;
    const int b = blockIdx.y;

    for (int k = 0; k < NCLS; ++k) acc[k][tid] = make_float2(0.f, 0.f);
    __syncthreads();

    const float4* xp = (const float4*)(x + ((size_t)(b * NCH + c)) * NPIX);
    const int4*   yp = (const int4*)(y + (size_t)b * NPIX);

    for (int it = 0; it < NPIX / (TPB * 4); ++it) {   // 64 iterations
        const int idx = it * TPB + tid;
        float4 v = xp[idx];
        int4   l = yp[idx];
        if ((unsigned)l.x < NCLS) { float2 t = acc[l.x][tid]; t.x += v.x; t.y = fmaf(v.x, v.x, t.y); acc[l.x][tid] = t; }
        if ((unsigned)l.y < NCLS) { float2 t = acc[l.y][tid]; t.x += v.y; t.y = fmaf(v.y, v.y, t.y); acc[l.y][tid] = t; }
        if ((unsigned)l.z < NCLS) { float2 t = acc[l.z][tid]; t.x += v.z; t.y = fmaf(v.z, v.z, t.y); acc[l.z][tid] = t; }
        if ((unsigned)l.w < NCLS) { float2 t = acc[l.w][tid]; t.x += v.w; t.y = fmaf(v.w, v.w, t.y); acc[l.w][tid] = t; }
    }

    // tree reduce over the 256 private copies
    for (int s = TPB / 2; s > 0; s >>= 1) {
        __syncthreads();
        if (tid < s) {
            for (int k = 0; k < NCLS; ++k) {
                float2 a = acc[k][tid];
                float2 o = acc[k][tid + s];
                a.x += o.x; a.y += o.y;
                acc[k][tid] = a;
            }
        }
    }
    __syncthreads();

    if (tid < NCLS) {
        const int k = tid;
        const float n = (float)counts[b * NCLS + k];
        const bool valid = n > (float)CNT_THRESH;
        float2 t = acc[k][0];
        float mean = t.x / fmaxf(n, 1.0f);
        float denom = fmaxf(n - 1.0f, 1.0f);
        float var = fmaxf((t.y - n * mean * mean) / denom, 0.0f);
        float m_out = valid ? mean : 0.0f;
        float s_out = valid ? (sqrtf(var) + EPSV) : 0.0f;
        const int o = (b * NCLS + k) * NCH + c;
        out[o] = m_out;                            // means  [4,19,256]
        out[NBATCH * NCLS * NCH + o] = s_out;      // stds   [4,19,256]
    }
}

extern "C" void kernel_launch(void* const* d_in, const int* in_sizes, int n_in,
                              void* d_out, int out_size, void* d_ws, size_t ws_size,
                              hipStream_t stream) {
    const float* x = (const float*)d_in[0];
    const int*   y = (const int*)d_in[1];
    float* out = (float*)d_out;
    int* counts = (int*)d_ws;                                  // 4*19 ints
    float* valid_out = out + 2 * NBATCH * NCLS * NCH;          // offset 38912

    count_kernel<<<NBATCH, TPB, 0, stream>>>(y, counts, valid_out);

    dim3 grid(NCH, NBATCH);
    moment_kernel<<<grid, TPB, 0, stream>>>(x, y, counts, out);
}